// Round 4
// baseline (451.719 us; speedup 1.0000x reference)
//
#include <hip/hip_runtime.h>
#include <stdint.h>

typedef unsigned int  u32;
typedef unsigned short u16;
typedef __bf16 v8bf __attribute__((ext_vector_type(8)));
typedef float  v4f  __attribute__((ext_vector_type(4)));

#define N_INST 256
#define BATCH  128
#define IN_DIM 1024
#define L_DIM  512
#define M_TOT  (N_INST*BATCH)   // 32768

#define BM 128
#define BN 128       // packed (interleaved V/U) cols per block = 64 L pairs
#define BK 64        // bf16 elems = 128 B = 8 chunks of 16 B per row
#define KITERS (IN_DIM/BK)
#define GRID   2048

// ws layout:
//   [0, 64MB)            : x_bf16 [32768][1024]
//   [64MB, 66MB)         : Wpk bf16 [1024 packed rows][1024 k]; row n' = 2*l + (0=V,1=U)
//   [66MB, +128KB)       : score fp32 [M_TOT] (atomic-accumulated)
//   [.. +4B]             : done counter
#define XB_BYTES   ((size_t)M_TOT * IN_DIM * 2)      // 67108864
#define WPK_BYTES  ((size_t)1024 * IN_DIM * 2)       // 2097152
#define SCORE_BYTES ((size_t)M_TOT * 4)

// pack bf16(a) low16, bf16(b) high16 (RNE)
__device__ inline u32 f2bf_pk(float a, float b){
  u32 ua = __builtin_bit_cast(u32, a);
  u32 ub = __builtin_bit_cast(u32, b);
  ua = (ua + 0x7FFFu + ((ua >> 16) & 1u)) >> 16;
  ub = (ub + 0x7FFFu + ((ub >> 16) & 1u)) & 0xFFFF0000u;
  return ua | ub;
}

// async global->LDS, 16 B per lane; lds dst is wave-uniform base (+lane*16 by HW)
__device__ inline void gl2lds16(const u16* g, u16* l){
  __builtin_amdgcn_global_load_lds(
      (const __attribute__((address_space(1))) u32*)(g),
      (__attribute__((address_space(3))) u32*)(l), 16, 0, 0);
}

// fused prep: [0,16384) convert x; [16384,16896) pack V/U; 16896 zeroes score+counter
#define PREP_XBLKS 16384
__global__ void prep(const float* __restrict__ x, const float* __restrict__ v,
                     const float* __restrict__ u, u16* __restrict__ xb,
                     u16* __restrict__ wpk, float* __restrict__ score,
                     u32* __restrict__ counter){
  const int b = blockIdx.x;
  if (b < PREP_XBLKS){
    size_t o = ((size_t)b * 256 + threadIdx.x) * 8;
    float4 a0 = *reinterpret_cast<const float4*>(x + o);
    float4 a1 = *reinterpret_cast<const float4*>(x + o + 4);
    uint4 out;
    out.x = f2bf_pk(a0.x, a0.y); out.y = f2bf_pk(a0.z, a0.w);
    out.z = f2bf_pk(a1.x, a1.y); out.w = f2bf_pk(a1.z, a1.w);
    *reinterpret_cast<uint4*>(xb + o) = out;
  } else if (b < PREP_XBLKS + 512){
    int t = (b - PREP_XBLKS) * 256 + threadIdx.x;  // 131072 threads
    int o = t * 8;
    int np = o >> 10;
    int k0 = o & 1023;
    int l  = np >> 1;
    const float* src = (np & 1) ? u : v;
    u32 out[4];
#pragma unroll
    for (int i = 0; i < 4; ++i){
      float a = src[(size_t)(k0 + 2*i    ) * L_DIM + l];
      float c = src[(size_t)(k0 + 2*i + 1) * L_DIM + l];
      out[i] = f2bf_pk(a, c);
    }
    *reinterpret_cast<uint4*>(wpk + o) = make_uint4(out[0], out[1], out[2], out[3]);
  } else {
    float4 z = {0.f,0.f,0.f,0.f};
#pragma unroll
    for (int i = 0; i < 32; ++i)
      reinterpret_cast<float4*>(score)[threadIdx.x*32 + i] = z;
    if (threadIdx.x == 0) *counter = 0u;
  }
}

__launch_bounds__(256, 2)
__global__ void gemm_fused(const u16* __restrict__ xb, const u16* __restrict__ wpk,
                           const float* __restrict__ w, float* __restrict__ score,
                           u32* counter, float* __restrict__ out){
  // double-buffered, unpadded (global_load_lds); XOR chunk swizzle kills conflicts
  __shared__ __align__(16) u16 As[2][BM * BK];   // 32 KB
  __shared__ __align__(16) u16 Bs[2][BN * BK];   // 32 KB
  __shared__ float ssum[BM];
  __shared__ float red[N_INST];
  __shared__ u32 stick;

  const int tid  = threadIdx.x;
  // XCD-aware swizzle (round-robin dispatch: XCD = bid&7): each XCD owns a
  // contiguous 32-mblk slice across all nblk -> x tile reused 8x in its L2.
  const u32 bid  = blockIdx.x;          // 0..2047
  const int xcd  = bid & 7;
  const int slot = bid >> 3;            // 0..255
  const int nblk = slot & 7;
  const int mblk = xcd * 32 + (slot >> 3);
  const int m0   = mblk * BM;

  const int lane = tid & 63;
  const int wave = tid >> 6;
  const int wm   = (wave >> 1) * 64;
  const int wn   = (wave & 1) * 64;
  const int q    = lane >> 4;
  const int c    = lane & 15;

  if (tid < BM) ssum[tid] = 0.f;

  // staging: 16 regions of 1 KB per tile; region = wave*4+j covers rows reg*8..+7
  // lane i -> row_in_region rr=i>>3, LDS chunk i&7 holds global chunk (i&7)^rr
  const int rr = lane >> 3;
  const int cg = (lane & 7) ^ rr;          // swizzled source chunk (16 B units)
  const u16* ga = xb  + (size_t)m0 * IN_DIM;
  const u16* gb = wpk + (size_t)(nblk * BN) * IN_DIM;

  auto issue = [&](int kt, int pb){
    const int kb = kt * BK;
#pragma unroll
    for (int j = 0; j < 4; ++j){
      const int reg = wave * 4 + j;
      const int row = reg * 8 + rr;
      gl2lds16(ga + (size_t)row * IN_DIM + kb + cg * 8, &As[pb][reg * 512 + lane * 8]);
      gl2lds16(gb + (size_t)row * IN_DIM + kb + cg * 8, &Bs[pb][reg * 512 + lane * 8]);
    }
  };

  // hoisted swizzled fragment offsets (u16-element units), loop-invariant
  int aoff[2][4], boff[2][4];
#pragma unroll
  for (int kk = 0; kk < 2; ++kk)
#pragma unroll
    for (int i = 0; i < 4; ++i){
      const int ra = wm + i*16 + c;
      aoff[kk][i] = ra*64 + (((kk*4 + q) ^ (ra & 7)) * 8);
      const int rb = wn + i*16 + c;
      boff[kk][i] = rb*64 + (((kk*4 + q) ^ (rb & 7)) * 8);
    }

  v4f acc[4][4];
#pragma unroll
  for (int i = 0; i < 4; ++i)
#pragma unroll
    for (int j = 0; j < 4; ++j)
      acc[i][j] = (v4f){0.f, 0.f, 0.f, 0.f};

  issue(0, 0);
  for (int kt = 0; kt < KITERS; ++kt){
    const int pb = kt & 1;
    __syncthreads();                    // drains buf[pb] loads (vmcnt0) + sync
    if (kt + 1 < KITERS) issue(kt + 1, pb ^ 1);   // in flight across compute
    const u16* a = As[pb];
    const u16* b = Bs[pb];
#pragma unroll
    for (int kk = 0; kk < 2; ++kk){
      v8bf af[4], bfr[4];
#pragma unroll
      for (int i = 0; i < 4; ++i){
        af[i]  = *reinterpret_cast<const v8bf*>(&a[aoff[kk][i]]);
        bfr[i] = *reinterpret_cast<const v8bf*>(&b[boff[kk][i]]);
      }
#pragma unroll
      for (int i = 0; i < 4; ++i)
#pragma unroll
        for (int j = 0; j < 4; ++j)
          acc[i][j] = __builtin_amdgcn_mfma_f32_16x16x32_bf16(af[i], bfr[j], acc[i][j], 0, 0, 0);
    }
    // no trailing barrier: next iteration's leading barrier covers the hazards
  }

  // epilogue: contrib = tanh(h)*sigmoid(g)*w[l]; packed cols alternate V(even)/U(odd)
  float wl[4];
#pragma unroll
  for (int j = 0; j < 4; ++j)
    wl[j] = w[nblk*64 + (wn >> 1) + j*8 + (c >> 1)];

  const int codd = c & 1;
#pragma unroll
  for (int i = 0; i < 4; ++i){
    float rs[4] = {0.f, 0.f, 0.f, 0.f};
#pragma unroll
    for (int j = 0; j < 4; ++j){
#pragma unroll
      for (int r = 0; r < 4; ++r){
        float val = acc[i][j][r];
        float y = codd ? val : 2.f*val;
        float s = 1.f / (1.f + __expf(-y));
        float t = codd ? s : (2.f*s - 1.f);
        float part = __shfl_xor(t, 1, 64);
        rs[r] += codd ? 0.f : (t * part * wl[j]);
      }
    }
#pragma unroll
    for (int r = 0; r < 4; ++r){
      float v2 = rs[r];
      v2 += __shfl_xor(v2, 1, 64);
      v2 += __shfl_xor(v2, 2, 64);
      v2 += __shfl_xor(v2, 4, 64);
      v2 += __shfl_xor(v2, 8, 64);
      if (c == 0) atomicAdd(&ssum[wm + i*16 + q*4 + r], v2);
    }
  }
  __syncthreads();
  if (tid < BM) atomicAdd(&score[m0 + tid], ssum[tid]);   // device-scope
  __threadfence();
  __syncthreads();   // vmcnt(0) drain: block's score RMWs complete at coherent point
  if (tid == 0){
    __threadfence();
    stick = atomicAdd(counter, 1);
  }
  __syncthreads();
  const u32 t = stick;

  // last BATCH tickets perform the softmax, one batch column each
  if (t >= (u32)(GRID - BATCH)){
    const int b = (int)t - (GRID - BATCH);
    if (tid == 0){
      while (__hip_atomic_load(counter, __ATOMIC_RELAXED, __HIP_MEMORY_SCOPE_AGENT) < (u32)GRID)
        __builtin_amdgcn_s_sleep(8);
    }
    __syncthreads();
    __threadfence();
    float s = __hip_atomic_load(&score[tid*BATCH + b], __ATOMIC_RELAXED, __HIP_MEMORY_SCOPE_AGENT);
    red[tid] = s; __syncthreads();
    for (int st = N_INST/2; st > 0; st >>= 1){
      if (tid < st) red[tid] = fmaxf(red[tid], red[tid + st]);
      __syncthreads();
    }
    float mx = red[0]; __syncthreads();
    float e = __expf(s - mx);
    red[tid] = e; __syncthreads();
    for (int st = N_INST/2; st > 0; st >>= 1){
      if (tid < st) red[tid] += red[tid + st];
      __syncthreads();
    }
    out[tid*BATCH + b] = e / red[0];
  }
}

extern "C" void kernel_launch(void* const* d_in, const int* in_sizes, int n_in,
                              void* d_out, int out_size, void* d_ws, size_t ws_size,
                              hipStream_t stream) {
  const float* x = (const float*)d_in[0];
  const float* v = (const float*)d_in[1];
  const float* u = (const float*)d_in[2];
  const float* w = (const float*)d_in[3];
  u16*   xb      = (u16*)d_ws;
  u16*   wpk     = (u16*)((char*)d_ws + XB_BYTES);
  float* score   = (float*)((char*)d_ws + XB_BYTES + WPK_BYTES);
  u32*   counter = (u32*)((char*)d_ws + XB_BYTES + WPK_BYTES + SCORE_BYTES);
  float* out     = (float*)d_out;

  prep<<<dim3(PREP_XBLKS + 512 + 1), dim3(256), 0, stream>>>(x, v, u, xb, wpk, score, counter);
  gemm_fused<<<dim3(GRID), dim3(256), 0, stream>>>(xb, wpk, w, score, counter, out);
}

// Round 5
// 314.480 us; speedup vs baseline: 1.4364x; 1.4364x over previous
//
#include <hip/hip_runtime.h>
#include <stdint.h>

typedef unsigned int  u32;
typedef unsigned short u16;
typedef __bf16 v8bf __attribute__((ext_vector_type(8)));
typedef float  v4f  __attribute__((ext_vector_type(4)));

#define N_INST 256
#define BATCH  128
#define IN_DIM 1024
#define L_DIM  512
#define M_TOT  (N_INST*BATCH)   // 32768

#define BM 128
#define BN 128       // packed cols per block (j-tiles alternate V/U, 64 l values)
#define BK 64        // bf16 elems = 128 B = 8 chunks of 16 B per row
#define KITERS (IN_DIM/BK)
#define NSLICE 16    // partial slices (8 nblk x 2 wn-halves)

// ws layout:
//   [0, 64MB)        : x_bf16 [32768][1024]
//   [64MB, 66MB)     : Wpk bf16 [1024 packed rows][1024 k]
//                      row p: b=p>>4, cc=p&15; b even -> V, b odd -> U; l=(b>>1)*16+cc
//   [66MB, 68MB)     : partial fp32 [16][M_TOT] (plain stores, fully covered)
#define XB_BYTES   ((size_t)M_TOT * IN_DIM * 2)      // 67108864
#define WPK_BYTES  ((size_t)1024 * IN_DIM * 2)       // 2097152

// pack bf16(a) low16, bf16(b) high16 (RNE)
__device__ inline u32 f2bf_pk(float a, float b){
  u32 ua = __builtin_bit_cast(u32, a);
  u32 ub = __builtin_bit_cast(u32, b);
  ua = (ua + 0x7FFFu + ((ua >> 16) & 1u)) >> 16;
  ub = (ub + 0x7FFFu + ((ub >> 16) & 1u)) & 0xFFFF0000u;
  return ua | ub;
}

// async global->LDS, 16 B per lane; lds dst is wave-uniform base (+lane*16 by HW)
__device__ inline void gl2lds16(const u16* g, u16* l){
  __builtin_amdgcn_global_load_lds(
      (const __attribute__((address_space(1))) u32*)(g),
      (__attribute__((address_space(3))) u32*)(l), 16, 0, 0);
}

// fused prep: [0,16384) convert x -> bf16; [16384,16896) pack V/U j-tile-separated
#define PREP_XBLKS 16384
__global__ void prep(const float* __restrict__ x, const float* __restrict__ v,
                     const float* __restrict__ u, u16* __restrict__ xb,
                     u16* __restrict__ wpk){
  const int b = blockIdx.x;
  if (b < PREP_XBLKS){
    size_t o = ((size_t)b * 256 + threadIdx.x) * 8;
    float4 a0 = *reinterpret_cast<const float4*>(x + o);
    float4 a1 = *reinterpret_cast<const float4*>(x + o + 4);
    uint4 out;
    out.x = f2bf_pk(a0.x, a0.y); out.y = f2bf_pk(a0.z, a0.w);
    out.z = f2bf_pk(a1.x, a1.y); out.w = f2bf_pk(a1.z, a1.w);
    *reinterpret_cast<uint4*>(xb + o) = out;
  } else {
    int t = (b - PREP_XBLKS) * 256 + threadIdx.x;  // 131072 threads
    int o = t * 8;
    int np = o >> 10;                               // packed row p
    int k0 = o & 1023;
    int l  = ((np >> 5) << 4) | (np & 15);          // l = (b>>1)*16 + cc
    const float* src = ((np >> 4) & 1) ? u : v;     // b odd -> U
    u32 out[4];
#pragma unroll
    for (int i = 0; i < 4; ++i){
      float a = src[(size_t)(k0 + 2*i    ) * L_DIM + l];
      float c = src[(size_t)(k0 + 2*i + 1) * L_DIM + l];
      out[i] = f2bf_pk(a, c);
    }
    *reinterpret_cast<uint4*>(wpk + o) = make_uint4(out[0], out[1], out[2], out[3]);
  }
}

__launch_bounds__(256)
__global__ void gemm_score(const u16* __restrict__ xb, const u16* __restrict__ wpk,
                           const float* __restrict__ w, float* __restrict__ partial){
  // exactly 32 KB LDS -> 5 blocks/CU; unpadded (global_load_lds); XOR chunk swizzle
  __shared__ __align__(16) u16 As[BM * BK];   // 16 KB
  __shared__ __align__(16) u16 Bs[BN * BK];   // 16 KB

  const int tid  = threadIdx.x;
  const int nblk = blockIdx.x;     // 0..7  (round-robin XCD: B-slice L2-resident)
  const int mblk = blockIdx.y;     // 0..255
  const int m0   = mblk * BM;

  const int lane = tid & 63;
  const int wave = tid >> 6;
  const int wm   = (wave >> 1) * 64;
  const int wn   = (wave & 1) * 64;
  const int q    = lane >> 4;
  const int c    = lane & 15;

  // staging: 16 regions of 1 KB per tile; region = wave*4+j covers rows reg*8..+7
  // lane i -> row_in_region rr=i>>3, LDS chunk i&7 holds global chunk (i&7)^rr
  const int rr = lane >> 3;
  const int cg = (lane & 7) ^ rr;          // swizzled source chunk (16 B units)
  const u16* ga = xb  + (size_t)m0 * IN_DIM;
  const u16* gb = wpk + (size_t)(nblk * BN) * IN_DIM;

  // hoisted swizzled fragment offsets for kk=0 (u16 units); kk=1 is ^32
  int aoff[4], boff[4];
#pragma unroll
  for (int i = 0; i < 4; ++i){
    const int ra = wm + i*16 + c;
    aoff[i] = ra*64 + ((q ^ (ra & 7)) * 8);
    const int rb = wn + i*16 + c;
    boff[i] = rb*64 + ((q ^ (rb & 7)) * 8);
  }

  v4f acc[4][4];
#pragma unroll
  for (int i = 0; i < 4; ++i)
#pragma unroll
    for (int j = 0; j < 4; ++j)
      acc[i][j] = (v4f){0.f, 0.f, 0.f, 0.f};

  for (int kt = 0; kt < KITERS; ++kt){
    const int kb = kt * BK;
#pragma unroll
    for (int j = 0; j < 4; ++j){
      const int reg = wave * 4 + j;
      const int row = reg * 8 + rr;
      gl2lds16(ga + (size_t)row * IN_DIM + kb + cg * 8, &As[reg * 512 + lane * 8]);
      gl2lds16(gb + (size_t)row * IN_DIM + kb + cg * 8, &Bs[reg * 512 + lane * 8]);
    }
    __syncthreads();   // drains vmcnt; tile visible to all waves
#pragma unroll
    for (int kk = 0; kk < 2; ++kk){
      v8bf af[4], bfr[4];
#pragma unroll
      for (int i = 0; i < 4; ++i){
        af[i]  = *reinterpret_cast<const v8bf*>(&As[aoff[i] ^ (kk*32)]);
        bfr[i] = *reinterpret_cast<const v8bf*>(&Bs[boff[i] ^ (kk*32)]);
      }
#pragma unroll
      for (int i = 0; i < 4; ++i)
#pragma unroll
        for (int j = 0; j < 4; ++j)
          acc[i][j] = __builtin_amdgcn_mfma_f32_16x16x32_bf16(af[i], bfr[j], acc[i][j], 0, 0, 0);
    }
    __syncthreads();   // protect LDS before next tile's loads
  }

  // epilogue (shuffle-free pairing): j even = tanh operand, j odd = sigmoid operand,
  // same l within a lane. l = nblk*64 + (wn>>5)*16 + c (+16 for pair 1).
  const int lbase = nblk*64 + (wn >> 5)*16 + c;
  const float wl0 = w[lbase];
  const float wl1 = w[lbase + 16];
  const int p = nblk*2 + (wn >> 6);       // partial slice
  float* pout = partial + (size_t)p * M_TOT + m0 + wm;

#pragma unroll
  for (int i = 0; i < 4; ++i){
#pragma unroll
    for (int r = 0; r < 4; ++r){
      float t0 = 2.f / (1.f + __expf(-2.f * acc[i][0][r])) - 1.f;
      float s0 = 1.f / (1.f + __expf(-acc[i][1][r]));
      float t1 = 2.f / (1.f + __expf(-2.f * acc[i][2][r])) - 1.f;
      float s1 = 1.f / (1.f + __expf(-acc[i][3][r]));
      float v2 = t0*s0*wl0 + t1*s1*wl1;
      v2 += __shfl_xor(v2, 1, 64);
      v2 += __shfl_xor(v2, 2, 64);
      v2 += __shfl_xor(v2, 4, 64);
      v2 += __shfl_xor(v2, 8, 64);
      if (c == 0) pout[i*16 + q*4 + r] = v2;   // plain store, slice-private rows
    }
  }
}

__global__ void softmax_inst(const float* __restrict__ partial, float* __restrict__ out){
  __shared__ float red[N_INST];
  const int b = blockIdx.x;
  const int n = threadIdx.x;
  float s = 0.f;
#pragma unroll
  for (int i = 0; i < NSLICE; ++i) s += partial[(size_t)i * M_TOT + n*BATCH + b];
  red[n] = s; __syncthreads();
  for (int st = N_INST/2; st > 0; st >>= 1){
    if (n < st) red[n] = fmaxf(red[n], red[n + st]);
    __syncthreads();
  }
  float mx = red[0]; __syncthreads();
  float e = __expf(s - mx);
  red[n] = e; __syncthreads();
  for (int st = N_INST/2; st > 0; st >>= 1){
    if (n < st) red[n] += red[n + st];
    __syncthreads();
  }
  out[n*BATCH + b] = e / red[0];
}

extern "C" void kernel_launch(void* const* d_in, const int* in_sizes, int n_in,
                              void* d_out, int out_size, void* d_ws, size_t ws_size,
                              hipStream_t stream) {
  const float* x = (const float*)d_in[0];
  const float* v = (const float*)d_in[1];
  const float* u = (const float*)d_in[2];
  const float* w = (const float*)d_in[3];
  u16*   xb      = (u16*)d_ws;
  u16*   wpk     = (u16*)((char*)d_ws + XB_BYTES);
  float* partial = (float*)((char*)d_ws + XB_BYTES + WPK_BYTES);
  float* out     = (float*)d_out;

  prep<<<dim3(PREP_XBLKS + 512), dim3(256), 0, stream>>>(x, v, u, xb, wpk);
  gemm_score<<<dim3(8, 256), dim3(256), 0, stream>>>(xb, wpk, w, partial);
  softmax_inst<<<dim3(BATCH), dim3(N_INST), 0, stream>>>(partial, out);
}

// Round 6
// 303.353 us; speedup vs baseline: 1.4891x; 1.0367x over previous
//
#include <hip/hip_runtime.h>
#include <stdint.h>

typedef unsigned int  u32;
typedef unsigned short u16;
typedef __bf16 v8bf __attribute__((ext_vector_type(8)));
typedef float  v4f  __attribute__((ext_vector_type(4)));

#define N_INST 256
#define BATCH  128
#define IN_DIM 1024
#define L_DIM  512
#define M_TOT  (N_INST*BATCH)   // 32768

#define BM 128
#define BN 128
#define BK 64
#define KITERS (IN_DIM/BK)      // 16
#define NSLICE 16

// Fragment-tiled layouts (u16 units). Region = 1 KB = 64 lanes x 16 B.
//   A region (mblk, kt, h, i, kk): lane (q=l>>4, c=l&15) holds
//     x_bf16[row = mblk*128 + h*64 + i*16 + c][k = kt*64 + kk*32 + q*8 .. +8]
//   linear region index = (((mblk*16+kt)*2+h)*4+i)*2+kk
//   B region (nblk, kt, h, j, kk): same, packed-col p = nblk*128+h*64+j*16+c,
//     bcol = p>>4 (even=V, odd=U), l = (bcol>>1)*16 + c
// ws: [0,64MB) xb_tiled; [64MB,66MB) wpk_tiled; [66MB,68MB) partial [16][M_TOT]
#define XB_BYTES   ((size_t)M_TOT * IN_DIM * 2)
#define WPK_BYTES  ((size_t)1024 * IN_DIM * 2)

__device__ inline u32 f2bf_pk(float a, float b){
  u32 ua = __builtin_bit_cast(u32, a);
  u32 ub = __builtin_bit_cast(u32, b);
  ua = (ua + 0x7FFFu + ((ua >> 16) & 1u)) >> 16;
  ub = (ub + 0x7FFFu + ((ub >> 16) & 1u)) & 0xFFFF0000u;
  return ua | ub;
}

// fused prep: [0,16384) x -> fragment-tiled bf16; [16384,16896) V/U -> fragment-tiled
#define PREP_XBLKS 16384
__global__ void prep(const float* __restrict__ x, const float* __restrict__ v,
                     const float* __restrict__ u, u16* __restrict__ xb,
                     u16* __restrict__ wpk){
  const int b = blockIdx.x;
  if (b < PREP_XBLKS){
    int t = b * 256 + threadIdx.x;          // region-major: writes fully coalesced
    int r = t >> 6, l = t & 63;
    int kk = r & 1, i = (r >> 1) & 3, h = (r >> 3) & 1, kt = (r >> 4) & 15, mb = r >> 8;
    int q = l >> 4, c = l & 15;
    int row = mb*128 + h*64 + i*16 + c;
    int k0  = kt*64 + kk*32 + q*8;
    const float* src = x + (size_t)row * IN_DIM + k0;
    float4 a0 = *reinterpret_cast<const float4*>(src);
    float4 a1 = *reinterpret_cast<const float4*>(src + 4);
    uint4 out;
    out.x = f2bf_pk(a0.x, a0.y); out.y = f2bf_pk(a0.z, a0.w);
    out.z = f2bf_pk(a1.x, a1.y); out.w = f2bf_pk(a1.z, a1.w);
    *reinterpret_cast<uint4*>(xb + (size_t)r*512 + l*8) = out;
  } else {
    int t = (b - PREP_XBLKS) * 256 + threadIdx.x;   // 131072 threads
    int r = t >> 6, l = t & 63;
    int kk = r & 1, j = (r >> 1) & 3, h = (r >> 3) & 1, kt = (r >> 4) & 15, nb = r >> 8;
    int q = l >> 4, c = l & 15;
    int bcol = nb*8 + h*4 + j;
    const float* src = (bcol & 1) ? u : v;
    int lcol = (bcol >> 1)*16 + c;
    int k0 = kt*64 + kk*32 + q*8;
    u32 o[4];
#pragma unroll
    for (int ii = 0; ii < 4; ++ii){
      float a  = src[(size_t)(k0 + 2*ii    ) * L_DIM + lcol];
      float bb = src[(size_t)(k0 + 2*ii + 1) * L_DIM + lcol];
      o[ii] = f2bf_pk(a, bb);
    }
    *reinterpret_cast<uint4*>(wpk + (size_t)r*512 + l*8) = make_uint4(o[0], o[1], o[2], o[3]);
  }
}

__launch_bounds__(256)
__global__ void gemm_score(const u16* __restrict__ xb, const u16* __restrict__ wpk,
                           const float* __restrict__ w, float* __restrict__ partial){
  // NO LDS, NO barriers: fragments load straight from (pre-swizzled) global.
  const int tid  = threadIdx.x;
  // XCD swizzle: same-XCD slots cycle nblk with mblk held -> A tile L2-resident
  const u32 bid  = blockIdx.x;          // 0..2047
  const int xcd  = bid & 7;
  const int slot = bid >> 3;
  const int nblk = slot & 7;
  const int mblk = xcd * 32 + (slot >> 3);
  const int m0   = mblk * BM;

  const int lane = tid & 63;
  const int wave = tid >> 6;
  const int ha   = wave >> 1;           // A half (rows ha*64..)
  const int hb   = wave & 1;            // B half (cols hb*64..)
  const int q    = lane >> 4;
  const int c    = lane & 15;

  const u16* pa = xb  + (size_t)mblk*131072 + ha*4096 + lane*8;
  const u16* pb = wpk + (size_t)nblk*131072 + hb*4096 + lane*8;

  v4f acc[4][4];
#pragma unroll
  for (int i = 0; i < 4; ++i)
#pragma unroll
    for (int j = 0; j < 4; ++j)
      acc[i][j] = (v4f){0.f, 0.f, 0.f, 0.f};

#pragma unroll 1
  for (int kt = 0; kt < KITERS; ++kt){
    const u16* a = pa + kt*8192;
    const u16* b = pb + kt*8192;
    v8bf af[8], bfr[8];
#pragma unroll
    for (int f = 0; f < 8; ++f){
      af[f]  = *reinterpret_cast<const v8bf*>(a + f*512);
      bfr[f] = *reinterpret_cast<const v8bf*>(b + f*512);
    }
#pragma unroll
    for (int kk = 0; kk < 2; ++kk)
#pragma unroll
      for (int i = 0; i < 4; ++i)
#pragma unroll
        for (int j = 0; j < 4; ++j)
          acc[i][j] = __builtin_amdgcn_mfma_f32_16x16x32_bf16(af[i*2+kk], bfr[j*2+kk], acc[i][j], 0, 0, 0);
  }

  // epilogue: j even = tanh (V), j odd = sigmoid (U), pairs share l within a lane
  const int lbase = nblk*64 + hb*32 + c;
  const float wl0 = w[lbase];
  const float wl1 = w[lbase + 16];
  const int p = nblk*2 + hb;
  float* pout = partial + (size_t)p * M_TOT + m0 + ha*64;

#pragma unroll
  for (int i = 0; i < 4; ++i){
#pragma unroll
    for (int r = 0; r < 4; ++r){
      float t0 = 2.f / (1.f + __expf(-2.f * acc[i][0][r])) - 1.f;
      float s0 = 1.f / (1.f + __expf(-acc[i][1][r]));
      float t1 = 2.f / (1.f + __expf(-2.f * acc[i][2][r])) - 1.f;
      float s1 = 1.f / (1.f + __expf(-acc[i][3][r]));
      float v2 = t0*s0*wl0 + t1*s1*wl1;
      v2 += __shfl_xor(v2, 1, 64);
      v2 += __shfl_xor(v2, 2, 64);
      v2 += __shfl_xor(v2, 4, 64);
      v2 += __shfl_xor(v2, 8, 64);
      if (c == 0) pout[i*16 + q*4 + r] = v2;   // slice-private rows, plain store
    }
  }
}

__global__ void softmax_inst(const float* __restrict__ partial, float* __restrict__ out){
  __shared__ float red[N_INST];
  const int b = blockIdx.x;
  const int n = threadIdx.x;
  float s = 0.f;
#pragma unroll
  for (int i = 0; i < NSLICE; ++i) s += partial[(size_t)i * M_TOT + n*BATCH + b];
  red[n] = s; __syncthreads();
  for (int st = N_INST/2; st > 0; st >>= 1){
    if (n < st) red[n] = fmaxf(red[n], red[n + st]);
    __syncthreads();
  }
  float mx = red[0]; __syncthreads();
  float e = __expf(s - mx);
  red[n] = e; __syncthreads();
  for (int st = N_INST/2; st > 0; st >>= 1){
    if (n < st) red[n] += red[n + st];
    __syncthreads();
  }
  out[n*BATCH + b] = e / red[0];
}

extern "C" void kernel_launch(void* const* d_in, const int* in_sizes, int n_in,
                              void* d_out, int out_size, void* d_ws, size_t ws_size,
                              hipStream_t stream) {
  const float* x = (const float*)d_in[0];
  const float* v = (const float*)d_in[1];
  const float* u = (const float*)d_in[2];
  const float* w = (const float*)d_in[3];
  u16*   xb      = (u16*)d_ws;
  u16*   wpk     = (u16*)((char*)d_ws + XB_BYTES);
  float* partial = (float*)((char*)d_ws + XB_BYTES + WPK_BYTES);
  float* out     = (float*)d_out;

  prep<<<dim3(PREP_XBLKS + 512), dim3(256), 0, stream>>>(x, v, u, xb, wpk);
  gemm_score<<<dim3(2048), dim3(256), 0, stream>>>(xb, wpk, w, partial);
  softmax_inst<<<dim3(BATCH), dim3(N_INST), 0, stream>>>(partial, out);
}